// Round 1
// baseline (1215.330 us; speedup 1.0000x reference)
//
#include <hip/hip_runtime.h>
#include <math.h>

// RWKV-6 chunked scan. B=4 H=32 T=2048 K=V=64.
// Phase 1: per (bh, chunk): local state S_c (from zero), decay product A_c,
//          and dec = exp(w) materialized for phase 3.  lane = k.
// Phase 2: inter-chunk scan (in-place: S slot becomes chunk-START state),
//          writes final_state.  lane = k.
// Phase 3: replay chunk from start state, emit o.  lane = v.

#define Bdim 4
#define Hdim 32
#define Tdim 2048
#define Kdim 64
#define Vdim 64
#define NC   16
#define CL   (Tdim / NC)   // 128

__global__ __launch_bounds__(64) void phase1_kernel(
    const float* __restrict__ kin, const float* __restrict__ vin,
    const float* __restrict__ win,
    float* __restrict__ S, float* __restrict__ A, float* __restrict__ dec)
{
    const int blk  = blockIdx.x;
    const int bh   = blk >> 4;          // NC = 16
    const int c    = blk & (NC - 1);
    const int lane = threadIdx.x;       // k index

    float hst[Vdim];
#pragma unroll
    for (int vv = 0; vv < Vdim; ++vv) hst[vv] = 0.0f;
    float Acc = 1.0f;

    const size_t base = ((size_t)bh * Tdim + (size_t)c * CL) * Kdim;
    const float* kp = kin + base;
    const float* wp = win + base;
    const float* vp = vin + base;
    float*       dp = dec + base;

    for (int t = 0; t < CL; ++t) {
        const float kk = kp[t * Kdim + lane];
        const float ww = wp[t * Kdim + lane];
        const float d  = __expf(ww);
        dp[t * Kdim + lane] = d;
        Acc *= d;
        const float* vt = vp + t * Kdim;   // uniform address -> s_load
#pragma unroll
        for (int vv = 0; vv < Vdim; ++vv) {
            const float sv = vt[vv];
            hst[vv] = fmaf(hst[vv], d, kk * sv);
        }
    }

    // S layout: [bh][c][v][k]  (k contiguous -> coalesced store over lanes)
    float* Sp = S + (size_t)(bh * NC + c) * (Vdim * Kdim);
#pragma unroll
    for (int vv = 0; vv < Vdim; ++vv)
        Sp[vv * Kdim + lane] = hst[vv];
    A[(bh * NC + c) * Kdim + lane] = Acc;
}

__global__ __launch_bounds__(64) void phase2_kernel(
    const float* __restrict__ init, float* __restrict__ S,
    const float* __restrict__ A, float* __restrict__ fin)
{
    const int bh   = blockIdx.x;
    const int lane = threadIdx.x;   // k index

    float hst[Vdim];
    const float* ip = init + (size_t)bh * Kdim * Vdim + (size_t)lane * Vdim;
#pragma unroll
    for (int vv = 0; vv < Vdim; ++vv) hst[vv] = ip[vv];

    for (int c = 0; c < NC; ++c) {
        float* Sp = S + (size_t)(bh * NC + c) * (Vdim * Kdim);
        const float Ac = A[(bh * NC + c) * Kdim + lane];
#pragma unroll
        for (int vv = 0; vv < Vdim; ++vv) {
            const float s = Sp[vv * Kdim + lane];
            Sp[vv * Kdim + lane] = hst[vv];           // state at chunk START
            hst[vv] = fmaf(hst[vv], Ac, s);
        }
    }

    float* fp = fin + (size_t)bh * Kdim * Vdim + (size_t)lane * Vdim;
#pragma unroll
    for (int vv = 0; vv < Vdim; ++vv) fp[vv] = hst[vv];
}

__global__ __launch_bounds__(64) void phase3_kernel(
    const float* __restrict__ rin, const float* __restrict__ kin,
    const float* __restrict__ vin, const float* __restrict__ uin,
    const float* __restrict__ S, const float* __restrict__ dec,
    float* __restrict__ oout)
{
    const int blk   = blockIdx.x;
    const int bh    = blk >> 4;
    const int c     = blk & (NC - 1);
    const int h_idx = bh & (Hdim - 1);
    const int lane  = threadIdx.x;   // v index

    // chunk-start state for this v: h0[k]
    float hst[Kdim];
    const float* Sp = S + ((size_t)(bh * NC + c) * Vdim + lane) * Kdim;
#pragma unroll
    for (int kk = 0; kk < Kdim; ++kk) hst[kk] = Sp[kk];

    const float* up = uin + h_idx * Kdim;   // uniform -> SGPRs

    const size_t base = ((size_t)bh * Tdim + (size_t)c * CL) * Kdim;
    const float* rp = rin + base;
    const float* kp = kin + base;
    const float* vp = vin + base;
    const float* dp = dec + base;
    float*       op = oout + base;

    for (int t = 0; t < CL; ++t) {
        const float vv = vp[t * Kdim + lane];
        const float* rt = rp + t * Kdim;   // uniform rows -> s_load
        const float* kt = kp + t * Kdim;
        const float* dt = dp + t * Kdim;
        float acc = 0.0f;
#pragma unroll
        for (int kk = 0; kk < Kdim; ++kk) {
            const float sq = rt[kk];
            const float sk = kt[kk];
            const float sd = dt[kk];
            const float p  = sk * vv;                    // k_t[k] * v_t[v]
            const float tt = fmaf(p, up[kk], hst[kk]);   // h + kv*u
            acc = fmaf(tt, sq, acc);                     // · q
            hst[kk] = fmaf(hst[kk], sd, p);              // h = h*d + kv
        }
        op[t * Kdim + lane] = acc;
    }
}

extern "C" void kernel_launch(void* const* d_in, const int* in_sizes, int n_in,
                              void* d_out, int out_size, void* d_ws, size_t ws_size,
                              hipStream_t stream) {
    const float* r    = (const float*)d_in[0];
    const float* k    = (const float*)d_in[1];
    const float* v    = (const float*)d_in[2];
    const float* w    = (const float*)d_in[3];
    const float* u    = (const float*)d_in[4];
    const float* init = (const float*)d_in[5];

    float* o   = (float*)d_out;
    float* fin = o + (size_t)Bdim * Hdim * Tdim * Vdim;

    float* S   = (float*)d_ws;
    float* A   = S + (size_t)Bdim * Hdim * NC * Vdim * Kdim;   // 8,388,608 floats
    float* dec = A + (size_t)Bdim * Hdim * NC * Kdim;          // +131,072 floats
    // dec: 16,777,216 floats; total ws use ~101.2 MB

    phase1_kernel<<<Bdim * Hdim * NC, 64, 0, stream>>>(k, v, w, S, A, dec);
    phase2_kernel<<<Bdim * Hdim, 64, 0, stream>>>(init, S, A, fin);
    phase3_kernel<<<Bdim * Hdim * NC, 64, 0, stream>>>(r, k, v, u, S, dec, o);
}

// Round 2
// 508.426 us; speedup vs baseline: 2.3904x; 2.3904x over previous
//
#include <hip/hip_runtime.h>
#include <math.h>

// RWKV-6 chunked scan, round 2. B=4 H=32 T=2048 K=V=64.
// NC=32 chunks of CL=64. lane-coalesced loads + v_readlane broadcasts
// (no wave-uniform global loads in hot loops, no dec materialization).
// Phase 1: per (bh,c) local state S_c (from zero) + decay product A_c. lane=k.
// Phase 2: inter-chunk scan parallel over (bh,v); S slot becomes chunk-START
//          state; writes final_state. lane=k.
// Phase 3: replay chunk from start state, emit o. lane=v; r/k/w loaded
//          per-lane (lane=k role) and broadcast via readlane.

#define Bdim 4
#define Hdim 32
#define Tdim 2048
#define Kdim 64
#define Vdim 64
#define NC   32
#define CL   (Tdim / NC)   // 64

__device__ __forceinline__ float bcast(float x, int lane) {
    return __int_as_float(__builtin_amdgcn_readlane(__float_as_int(x), lane));
}

__global__ __launch_bounds__(64) void phase1_kernel(
    const float* __restrict__ kin, const float* __restrict__ vin,
    const float* __restrict__ win,
    float* __restrict__ S, float* __restrict__ A)
{
    const int blk  = blockIdx.x;
    const int bh   = blk >> 5;          // NC = 32
    const int c    = blk & (NC - 1);
    const int lane = threadIdx.x;       // k index

    float hst[Vdim];
#pragma unroll
    for (int vv = 0; vv < Vdim; ++vv) hst[vv] = 0.0f;
    float Acc = 1.0f;

    const size_t base = ((size_t)bh * Tdim + (size_t)c * CL) * Kdim;
    const float* kp = kin + base;
    const float* wp = win + base;
    const float* vp = vin + base;

    for (int t = 0; t < CL; ++t) {
        const float kk = kp[t * Kdim + lane];
        const float ww = wp[t * Kdim + lane];
        const float vt = vp[t * Kdim + lane];   // lane plays v-role for load
        const float d  = __expf(ww);
        Acc *= d;
#pragma unroll
        for (int vv = 0; vv < Vdim; ++vv) {
            const float sv = bcast(vt, vv);
            hst[vv] = fmaf(hst[vv], d, kk * sv);
        }
    }

    // S layout: [bh][c][v][k]  (k contiguous -> coalesced over lanes)
    float* Sp = S + (size_t)(bh * NC + c) * (Vdim * Kdim);
#pragma unroll
    for (int vv = 0; vv < Vdim; ++vv)
        Sp[vv * Kdim + lane] = hst[vv];
    A[(bh * NC + c) * Kdim + lane] = Acc;
}

// One wave per (bh, v). lane = k. All S/A accesses coalesced.
__global__ __launch_bounds__(256) void phase2_kernel(
    const float* __restrict__ init, float* __restrict__ S,
    const float* __restrict__ A, float* __restrict__ fin)
{
    const int gw   = blockIdx.x * 4 + (threadIdx.x >> 6);  // 0..8191
    const int lane = threadIdx.x & 63;                     // k index
    const int bh   = gw >> 6;
    const int v    = gw & 63;

    // init layout [bh][k][v]
    float h = init[(size_t)bh * Kdim * Vdim + (size_t)lane * Vdim + v];

    for (int c = 0; c < NC; ++c) {
        const size_t idx = (size_t)(bh * NC + c) * (Vdim * Kdim)
                         + (size_t)v * Kdim + lane;
        const float s = S[idx];
        S[idx] = h;                                  // state at chunk START
        h = fmaf(h, A[(bh * NC + c) * Kdim + lane], s);
    }

    fin[(size_t)bh * Kdim * Vdim + (size_t)lane * Vdim + v] = h;
}

__global__ __launch_bounds__(64) void phase3_kernel(
    const float* __restrict__ rin, const float* __restrict__ kin,
    const float* __restrict__ vin, const float* __restrict__ win,
    const float* __restrict__ uin,
    const float* __restrict__ S, float* __restrict__ oout)
{
    const int blk   = blockIdx.x;
    const int bh    = blk >> 5;
    const int c     = blk & (NC - 1);
    const int h_idx = bh & (Hdim - 1);
    const int lane  = threadIdx.x;   // v index

    // chunk-start state for this v: h0[k]
    float hst[Kdim];
    const float* Sp = S + ((size_t)(bh * NC + c) * Vdim + lane) * Kdim;
#pragma unroll
    for (int kk = 0; kk < Kdim; ++kk) hst[kk] = Sp[kk];

    // u row, forced uniform (SGPRs)
    const float* up = uin + h_idx * Kdim;
    float us[Kdim];
#pragma unroll
    for (int kk = 0; kk < Kdim; ++kk)
        us[kk] = __int_as_float(__builtin_amdgcn_readfirstlane(__float_as_int(up[kk])));

    const size_t base = ((size_t)bh * Tdim + (size_t)c * CL) * Kdim;
    const float* rp = rin + base;
    const float* kp = kin + base;
    const float* vp = vin + base;
    const float* wp = win + base;
    float*       op = oout + base;

    for (int t = 0; t < CL; ++t) {
        // lane plays the k-role for these loads (coalesced)
        const float rl = rp[t * Kdim + lane];
        const float kl = kp[t * Kdim + lane];
        const float wl = wp[t * Kdim + lane];
        const float vv = vp[t * Kdim + lane];   // lane = v (its real role)
        const float dl = __expf(wl);            // one exp per (t,k): no redundancy

        float acc = 0.0f;
#pragma unroll
        for (int kk = 0; kk < Kdim; ++kk) {
            const float sq = bcast(rl, kk);
            const float sk = bcast(kl, kk);
            const float sd = bcast(dl, kk);
            const float p  = sk * vv;                    // k_t[k] * v_t[v]
            const float tt = fmaf(p, us[kk], hst[kk]);   // h + kv*u
            acc = fmaf(tt, sq, acc);                     // · q
            hst[kk] = fmaf(hst[kk], sd, p);              // h = h*d + kv
        }
        op[t * Kdim + lane] = acc;
    }
}

extern "C" void kernel_launch(void* const* d_in, const int* in_sizes, int n_in,
                              void* d_out, int out_size, void* d_ws, size_t ws_size,
                              hipStream_t stream) {
    const float* r    = (const float*)d_in[0];
    const float* k    = (const float*)d_in[1];
    const float* v    = (const float*)d_in[2];
    const float* w    = (const float*)d_in[3];
    const float* u    = (const float*)d_in[4];
    const float* init = (const float*)d_in[5];

    float* o   = (float*)d_out;
    float* fin = o + (size_t)Bdim * Hdim * Tdim * Vdim;

    float* S = (float*)d_ws;                                   // 67.1 MB
    float* A = S + (size_t)Bdim * Hdim * NC * Vdim * Kdim;     // +1.0 MB

    phase1_kernel<<<Bdim * Hdim * NC, 64, 0, stream>>>(k, v, w, S, A);
    phase2_kernel<<<(Bdim * Hdim * Vdim) / 4, 256, 0, stream>>>(init, S, A, fin);
    phase3_kernel<<<Bdim * Hdim * NC, 64, 0, stream>>>(r, k, v, w, u, S, o);
}

// Round 3
// 393.396 us; speedup vs baseline: 3.0893x; 1.2924x over previous
//
#include <hip/hip_runtime.h>
#include <math.h>

// RWKV-6 chunked scan, round 3: MFMA formulation.  B=4 H=32 T=2048 K=V=64.
// NC=32 chunks of CL=64.  One 4-wave block per (bh, chunk).
// Exponent anchor Cmid = cw_31 keeps all live exponents within e^±64 (fp32-safe);
// masked-region overflow (inf) is discarded by the causal mask.
// Phase 1 (MFMA): S_c = Kbar^T V (chunk-local state from zero), A_c = e^{cw_63}.
// Phase 2 (fp32 VALU): inter-chunk scan; S slot becomes chunk-START state; final_state.
// Phase 3 (MFMA): A = Qhat Khat^T (masked, diag = sum_k q*u*k), o = A V + Qtilde h0.

#define Bdim 4
#define Hdim 32
#define Tdim 2048
#define Kdim 64
#define Vdim 64
#define NC   32
#define CL   64
#define LP   72   // padded LDS row stride (bf16 elems): 144 B, 16B-aligned

typedef __attribute__((ext_vector_type(8))) short short8;
typedef __attribute__((ext_vector_type(4))) float float4_;

__device__ __forceinline__ short f2bf(float x) {
    unsigned u = __float_as_uint(x);
    unsigned r = (u + 0x7FFFu + ((u >> 16) & 1u)) >> 16;
    return (short)r;
}

#define MFMA(a, b, c) __builtin_amdgcn_mfma_f32_16x16x32_bf16(a, b, c, 0, 0, 0)

// ---------------- Phase 1: chunk-local state via MFMA ----------------
__global__ __launch_bounds__(256) void phase1_mfma(
    const float* __restrict__ kin, const float* __restrict__ vin,
    const float* __restrict__ win,
    float* __restrict__ S, float* __restrict__ A)
{
    __shared__ __attribute__((aligned(16))) short Kb[CL * LP];  // Kbar[s][k]
    __shared__ __attribute__((aligned(16))) short Vv[CL * LP];  // V[s][v]
    __shared__ float bsum[4 * 64];

    const int tid  = threadIdx.x;
    const int w    = tid >> 6;       // wave 0..3 = t-block / v-tile
    const int lane = tid & 63;       // k index in preprocessing
    const int quad = lane >> 4, r = lane & 15;
    const int blk  = blockIdx.x;
    const int bh   = blk >> 5;
    const int c    = blk & (NC - 1);

    const size_t base = ((size_t)bh * Tdim + (size_t)c * CL) * Kdim;

    // pass 1: per-wave block-sum of w over its 16 t's
    float wreg[16];
    float cwl = 0.0f;
#pragma unroll
    for (int tt = 0; tt < 16; ++tt) {
        const int t = 16 * w + tt;
        const float ww = win[base + t * Kdim + lane];
        wreg[tt] = ww;
        cwl += ww;
    }
    bsum[w * 64 + lane] = cwl;
    __syncthreads();

    float pref = 0.0f;
#pragma unroll
    for (int j = 0; j < 4; ++j) if (j < w) pref += bsum[j * 64 + lane];
    const float tot = bsum[0 * 64 + lane] + bsum[1 * 64 + lane]
                    + bsum[2 * 64 + lane] + bsum[3 * 64 + lane];   // cw_63

    // pass 2: Kbar, V into LDS (bf16)
    float cwrun = pref;
#pragma unroll
    for (int tt = 0; tt < 16; ++tt) {
        const int t = 16 * w + tt;
        cwrun += wreg[tt];                       // cw_t (inclusive)
        const float kk = kin[base + t * Kdim + lane];
        const float vv = vin[base + t * Kdim + lane];
        Kb[t * LP + lane] = f2bf(kk * __expf(tot - cwrun));   // <= 1
        Vv[t * LP + lane] = f2bf(vv);
    }
    if (w == 0) A[(bh * NC + c) * Kdim + lane] = __expf(tot);
    __syncthreads();

    // S_c tiles: D[m=v][n=k] = sum_s V[s][v] * Kbar[s][k]
    // A-op: A[m=r][kd=quad*8+j] = V[quad*8+j][16w + r]   (strided u16 reads)
    short8 va0, va1;
#pragma unroll
    for (int j2 = 0; j2 < 8; ++j2) {
        va0[j2] = Vv[(quad * 8 + j2) * LP + 16 * w + r];
        va1[j2] = Vv[(32 + quad * 8 + j2) * LP + 16 * w + r];
    }
    float* Sp = S + (size_t)(bh * NC + c) * (Vdim * Kdim);
#pragma unroll
    for (int n = 0; n < 4; ++n) {
        short8 kb0, kb1;
#pragma unroll
        for (int j2 = 0; j2 < 8; ++j2) {
            kb0[j2] = Kb[(quad * 8 + j2) * LP + 16 * n + r];
            kb1[j2] = Kb[(32 + quad * 8 + j2) * LP + 16 * n + r];
        }
        float4_ acc = {0.0f, 0.0f, 0.0f, 0.0f};
        acc = MFMA(va0, kb0, acc);
        acc = MFMA(va1, kb1, acc);
        // store S[v][k]: v = 16w + quad*4 + reg, k = 16n + r
#pragma unroll
        for (int reg = 0; reg < 4; ++reg)
            Sp[(16 * w + quad * 4 + reg) * Kdim + 16 * n + r] = acc[reg];
    }
}

// ---------------- Phase 2: inter-chunk scan (unchanged, fp32) ----------------
__global__ __launch_bounds__(256) void phase2_kernel(
    const float* __restrict__ init, float* __restrict__ S,
    const float* __restrict__ A, float* __restrict__ fin)
{
    const int gw   = blockIdx.x * 4 + (threadIdx.x >> 6);  // 0..8191
    const int lane = threadIdx.x & 63;                     // k index
    const int bh   = gw >> 6;
    const int v    = gw & 63;

    float h = init[(size_t)bh * Kdim * Vdim + (size_t)lane * Vdim + v];

    for (int c = 0; c < NC; ++c) {
        const size_t idx = (size_t)(bh * NC + c) * (Vdim * Kdim)
                         + (size_t)v * Kdim + lane;
        const float s = S[idx];
        S[idx] = h;                                  // state at chunk START
        h = fmaf(h, A[(bh * NC + c) * Kdim + lane], s);
    }
    fin[(size_t)bh * Kdim * Vdim + (size_t)lane * Vdim + v] = h;
}

// ---------------- Phase 3: o via MFMA ----------------
__global__ __launch_bounds__(256) void phase3_mfma(
    const float* __restrict__ rin, const float* __restrict__ kin,
    const float* __restrict__ vin, const float* __restrict__ win,
    const float* __restrict__ uin,
    const float* __restrict__ S, float* __restrict__ oout)
{
    __shared__ __attribute__((aligned(16))) short Qh[CL * LP];  // Qhat[t][k]
    __shared__ __attribute__((aligned(16))) short Kh[CL * LP];  // Khat[s][k]
    __shared__ __attribute__((aligned(16))) short Qt[CL * LP];  // Qtilde[t][k]
    __shared__ __attribute__((aligned(16))) short Vv[CL * LP];  // V[t][v]
    __shared__ __attribute__((aligned(16))) short Am[CL * LP];  // masked A[t][s]
    __shared__ float Dd[CL];
    __shared__ float bsum[4 * 64];

    const int tid  = threadIdx.x;
    const int w    = tid >> 6;
    const int lane = tid & 63;
    const int quad = lane >> 4, r = lane & 15;
    const int blk  = blockIdx.x;
    const int bh   = blk >> 5;
    const int c    = blk & (NC - 1);
    const int h_idx = bh & (Hdim - 1);

    const size_t base = ((size_t)bh * Tdim + (size_t)c * CL) * Kdim;

    // zero A (upper-triangle region is never written by tiles)
    for (int i = tid; i < CL * LP; i += 256) Am[i] = 0;

    // pass 1: block-sums of w
    float wreg[16];
    float cwl = 0.0f;
#pragma unroll
    for (int tt = 0; tt < 16; ++tt) {
        const int t = 16 * w + tt;
        const float ww = win[base + t * Kdim + lane];
        wreg[tt] = ww;
        cwl += ww;
    }
    bsum[w * 64 + lane] = cwl;
    __syncthreads();

    float pref = 0.0f;
#pragma unroll
    for (int j = 0; j < 4; ++j) if (j < w) pref += bsum[j * 64 + lane];
    const float Cmid = bsum[0 * 64 + lane] + bsum[1 * 64 + lane];  // cw_31

    const float u_ = uin[h_idx * Kdim + lane];

    // pass 2: Qhat, Khat, Qtilde, V, D
    float cwrun = pref;                 // cw_{t-1} before first t of block
#pragma unroll
    for (int tt = 0; tt < 16; ++tt) {
        const int t = 16 * w + tt;
        const float cwp = cwrun;        // cw_{t-1} (exclusive)
        cwrun += wreg[tt];              // cw_t (inclusive)
        const float q = rin[base + t * Kdim + lane];
        const float k = kin[base + t * Kdim + lane];
        const float v = vin[base + t * Kdim + lane];
        Qh[t * LP + lane] = f2bf(q * __expf(cwp - Cmid));
        Kh[t * LP + lane] = f2bf(k * __expf(Cmid - cwrun));
        Qt[t * LP + lane] = f2bf(q * __expf(cwp));
        Vv[t * LP + lane] = f2bf(v);
        float d3 = q * u_ * k;
        for (int off = 32; off > 0; off >>= 1) d3 += __shfl_xor(d3, off);
        if (lane == 0) Dd[t] = d3;
    }
    __syncthreads();

    // A-phase: wave w computes score tiles (i=w, j<=w)
    {
        short8 qa0 = *(const short8*)&Qh[(16 * w + r) * LP + quad * 8];
        short8 qa1 = *(const short8*)&Qh[(16 * w + r) * LP + 32 + quad * 8];
        for (int j = 0; j <= w; ++j) {
            short8 kb0 = *(const short8*)&Kh[(16 * j + r) * LP + quad * 8];
            short8 kb1 = *(const short8*)&Kh[(16 * j + r) * LP + 32 + quad * 8];
            float4_ acc = {0.0f, 0.0f, 0.0f, 0.0f};
            acc = MFMA(qa0, kb0, acc);
            acc = MFMA(qa1, kb1, acc);
#pragma unroll
            for (int reg = 0; reg < 4; ++reg) {
                const int tg = 16 * w + quad * 4 + reg;
                const int sg = 16 * j + r;
                float val = (tg > sg) ? acc[reg] : ((tg == sg) ? Dd[tg] : 0.0f);
                Am[tg * LP + sg] = f2bf(val);
            }
        }
    }
    __syncthreads();

    // O-phase: wave w computes o rows [16w,16w+16): o = A V + Qtilde h0
    short8 aa0 = *(const short8*)&Am[(16 * w + r) * LP + quad * 8];
    short8 aa1 = *(const short8*)&Am[(16 * w + r) * LP + 32 + quad * 8];
    short8 qt0 = *(const short8*)&Qt[(16 * w + r) * LP + quad * 8];
    short8 qt1 = *(const short8*)&Qt[(16 * w + r) * LP + 32 + quad * 8];
    float* op = oout + base;

#pragma unroll
    for (int n = 0; n < 4; ++n) {
        short8 vb0, vb1;
#pragma unroll
        for (int j2 = 0; j2 < 8; ++j2) {
            vb0[j2] = Vv[(quad * 8 + j2) * LP + 16 * n + r];
            vb1[j2] = Vv[(32 + quad * 8 + j2) * LP + 16 * n + r];
        }
        // h0 B-frag straight from global S (layout [bh][c][v][k], v-major)
        const float* hp = S + ((size_t)(bh * NC + c) * Vdim + 16 * n + r) * Kdim;
        short8 hb0, hb1;
#pragma unroll
        for (int j2 = 0; j2 < 8; ++j2) {
            hb0[j2] = f2bf(hp[quad * 8 + j2]);
            hb1[j2] = f2bf(hp[32 + quad * 8 + j2]);
        }
        float4_ o4 = {0.0f, 0.0f, 0.0f, 0.0f};
        o4 = MFMA(aa0, vb0, o4);
        o4 = MFMA(aa1, vb1, o4);
        o4 = MFMA(qt0, hb0, o4);
        o4 = MFMA(qt1, hb1, o4);
#pragma unroll
        for (int reg = 0; reg < 4; ++reg)
            op[(16 * w + quad * 4 + reg) * Vdim + 16 * n + r] = o4[reg];
    }
}

extern "C" void kernel_launch(void* const* d_in, const int* in_sizes, int n_in,
                              void* d_out, int out_size, void* d_ws, size_t ws_size,
                              hipStream_t stream) {
    const float* r    = (const float*)d_in[0];
    const float* k    = (const float*)d_in[1];
    const float* v    = (const float*)d_in[2];
    const float* w    = (const float*)d_in[3];
    const float* u    = (const float*)d_in[4];
    const float* init = (const float*)d_in[5];

    float* o   = (float*)d_out;
    float* fin = o + (size_t)Bdim * Hdim * Tdim * Vdim;

    float* S = (float*)d_ws;                                   // 67.1 MB
    float* A = S + (size_t)Bdim * Hdim * NC * Vdim * Kdim;     // +0.5 MB

    phase1_mfma<<<Bdim * Hdim * NC, 256, 0, stream>>>(k, v, w, S, A);
    phase2_kernel<<<(Bdim * Hdim * Vdim) / 4, 256, 0, stream>>>(init, S, A, fin);
    phase3_mfma<<<Bdim * Hdim * NC, 256, 0, stream>>>(r, k, v, w, u, S, o);
}